// Round 1
// baseline (399.599 us; speedup 1.0000x reference)
//
#include <hip/hip_runtime.h>

#define D_NODE 64
#define H_DIM  128

// ---------------------------------------------------------------------------
// Kernel A: P[0:numS]      = emb_s @ W1[0:64,:]  + b1   (b1 baked into s-half)
//           P[numS:numS+A] = emb_a @ W1[64:128,:]
// One block = 128 threads (thread j owns output column j), 16 rows per block.
// W half-matrix (64 values per thread) hoisted into registers.
// ---------------------------------------------------------------------------
__global__ void __launch_bounds__(128)
precompute_P_kernel(const float* __restrict__ emb_s,
                    const float* __restrict__ emb_a,
                    const float* __restrict__ W1,
                    const float* __restrict__ b1,
                    float* __restrict__ P,
                    int numS, int numA)
{
    const int col = threadIdx.x;               // 0..127
    const int sBlocks = (numS + 15) / 16;
    const bool isS = ((int)blockIdx.x < sBlocks);

    const float* Wh = isS ? W1 : (W1 + D_NODE * H_DIM);
    float w[D_NODE];
#pragma unroll
    for (int k = 0; k < D_NODE; ++k) w[k] = Wh[k * H_DIM + col];

    const float bias = isS ? b1[col] : 0.0f;
    const int rowBase = (isS ? (int)blockIdx.x : ((int)blockIdx.x - sBlocks)) * 16;
    const float* etab = isS ? emb_s : emb_a;
    const int rowsTot = isS ? numS : numA;
    const int pOff = isS ? 0 : numS;

    for (int r = 0; r < 16; ++r) {
        const int row = rowBase + r;
        if (row >= rowsTot) break;
        const float* erow = etab + (size_t)row * D_NODE;
        float acc = bias;
#pragma unroll
        for (int k = 0; k < D_NODE; ++k)
            acc = fmaf(erow[k], w[k], acc);
        P[(size_t)(pOff + row) * H_DIM + col] = acc;
    }
}

// ---------------------------------------------------------------------------
// Kernel B: init segment max (bits of -inf) and segment sum (0)
// ---------------------------------------------------------------------------
__global__ void init_seg_kernel(unsigned* __restrict__ segmax,
                                float* __restrict__ segsum, int n)
{
    int i = blockIdx.x * blockDim.x + threadIdx.x;
    if (i < n) {
        segmax[i] = 0xFF800000u;   // -inf
        segsum[i] = 0.0f;
    }
}

// ---------------------------------------------------------------------------
// Kernel C: per-edge main pass.
//   cost = ||es-ea|| * sigmoid( dot(relu(P_s[s]+P_a[a]), W2) + b2 )
//   val  = -cost / exp(logT);  atomic segment max (uint-min trick, vals<=-0)
// One thread per edge; float4 gathers.
// ---------------------------------------------------------------------------
__global__ void __launch_bounds__(256)
edge_main_kernel(const float* __restrict__ emb_s,
                 const float* __restrict__ emb_a,
                 const int* __restrict__ idx,
                 const float* __restrict__ P,
                 const float* __restrict__ W2,
                 const float* __restrict__ b2,
                 const float* __restrict__ logT,
                 float* __restrict__ out_costs,   // d_out + E
                 float* __restrict__ vals,
                 unsigned* __restrict__ segmax,
                 int E, int numS)
{
    const int e = blockIdx.x * blockDim.x + threadIdx.x;
    if (e >= E) return;

    const int s = idx[e];
    const int a = idx[E + e];

    // --- norm over D=64 ---
    const float4* es4 = (const float4*)(emb_s + (size_t)s * D_NODE);
    const float4* ea4 = (const float4*)(emb_a + (size_t)a * D_NODE);
    float nacc = 0.0f;
#pragma unroll
    for (int k = 0; k < D_NODE / 4; ++k) {
        float4 x = es4[k];
        float4 y = ea4[k];
        float d0 = x.x - y.x, d1 = x.y - y.y, d2 = x.z - y.z, d3 = x.w - y.w;
        nacc = fmaf(d0, d0, nacc);
        nacc = fmaf(d1, d1, nacc);
        nacc = fmaf(d2, d2, nacc);
        nacc = fmaf(d3, d3, nacc);
    }
    const float nrm = sqrtf(nacc);

    // --- gate: relu(P_s + P_a) . W2 ---
    const float4* ps4 = (const float4*)(P + (size_t)s * H_DIM);
    const float4* pa4 = (const float4*)(P + (size_t)(numS + a) * H_DIM);
    const float4* w24 = (const float4*)W2;
    float g = 0.0f;
#pragma unroll
    for (int j = 0; j < H_DIM / 4; ++j) {
        float4 p = ps4[j];
        float4 q = pa4[j];
        float4 w = w24[j];
        float h0 = fmaxf(p.x + q.x, 0.0f);
        float h1 = fmaxf(p.y + q.y, 0.0f);
        float h2 = fmaxf(p.z + q.z, 0.0f);
        float h3 = fmaxf(p.w + q.w, 0.0f);
        g = fmaf(h0, w.x, g);
        g = fmaf(h1, w.y, g);
        g = fmaf(h2, w.z, g);
        g = fmaf(h3, w.w, g);
    }
    const float z = g + b2[0];
    const float gate = 1.0f / (1.0f + __expf(-z));
    const float cost = nrm * gate;

    out_costs[e] = cost;

    const float temp = __expf(logT[0]);
    const float val = -cost / temp;
    vals[e] = val;

    // max over negative floats == min over their uint bit patterns
    atomicMin(&segmax[s], __float_as_uint(val));
}

// ---------------------------------------------------------------------------
// Kernel D: ex = exp(val - segmax[s]); segment-sum via atomicAdd
// ---------------------------------------------------------------------------
__global__ void __launch_bounds__(256)
edge_exp_kernel(const int* __restrict__ idx,
                float* __restrict__ vals,          // in: val, out: ex
                const unsigned* __restrict__ segmax,
                float* __restrict__ segsum,
                int E)
{
    const int e = blockIdx.x * blockDim.x + threadIdx.x;
    if (e >= E) return;
    const int s = idx[e];
    const float m = __uint_as_float(segmax[s]);
    const float ex = __expf(vals[e] - m);
    vals[e] = ex;
    atomicAdd(&segsum[s], ex);
}

// ---------------------------------------------------------------------------
// Kernel E: edge_weights = ex / segsum[s]
// ---------------------------------------------------------------------------
__global__ void __launch_bounds__(256)
edge_norm_kernel(const int* __restrict__ idx,
                 const float* __restrict__ vals,   // ex
                 const float* __restrict__ segsum,
                 float* __restrict__ out_w,        // d_out + 0
                 int E)
{
    const int e = blockIdx.x * blockDim.x + threadIdx.x;
    if (e >= E) return;
    const int s = idx[e];
    out_w[e] = vals[e] / segsum[s];
}

// ---------------------------------------------------------------------------
extern "C" void kernel_launch(void* const* d_in, const int* in_sizes, int n_in,
                              void* d_out, int out_size, void* d_ws, size_t ws_size,
                              hipStream_t stream)
{
    const float* emb_s = (const float*)d_in[0];
    const float* emb_a = (const float*)d_in[1];
    const int*   idx   = (const int*)d_in[2];
    const float* W1    = (const float*)d_in[3];
    const float* b1    = (const float*)d_in[4];
    const float* W2    = (const float*)d_in[5];
    const float* b2    = (const float*)d_in[6];
    const float* logT  = (const float*)d_in[7];

    const int numS = in_sizes[0] / D_NODE;
    const int numA = in_sizes[1] / D_NODE;
    const int E    = in_sizes[2] / 2;

    float* out = (float*)d_out;            // [0,E) weights, [E,2E) costs

    // workspace layout
    char* ws = (char*)d_ws;
    const size_t szP = (size_t)(numS + numA) * H_DIM * sizeof(float);
    float*    P      = (float*)ws;
    float*    vals   = (float*)(ws + szP);
    unsigned* segmax = (unsigned*)(ws + szP + (size_t)E * sizeof(float));
    float*    segsum = (float*)(ws + szP + (size_t)E * sizeof(float)
                                        + (size_t)numS * sizeof(unsigned));

    const int pBlocks = (numS + 15) / 16 + (numA + 15) / 16;
    precompute_P_kernel<<<pBlocks, 128, 0, stream>>>(emb_s, emb_a, W1, b1, P,
                                                     numS, numA);

    init_seg_kernel<<<(numS + 255) / 256, 256, 0, stream>>>(segmax, segsum, numS);

    const int eBlocks = (E + 255) / 256;
    edge_main_kernel<<<eBlocks, 256, 0, stream>>>(emb_s, emb_a, idx, P, W2, b2,
                                                  logT, out + E, vals, segmax,
                                                  E, numS);

    edge_exp_kernel<<<eBlocks, 256, 0, stream>>>(idx, vals, segmax, segsum, E);

    edge_norm_kernel<<<eBlocks, 256, 0, stream>>>(idx, vals, segsum, out, E);
}

// Round 2
// 188.619 us; speedup vs baseline: 2.1186x; 2.1186x over previous
//
#include <hip/hip_runtime.h>
#include <hip/hip_fp16.h>

#define D_NODE 64
#define H_DIM  128

// ---------------------------------------------------------------------------
// fp32 -> fp16 table conversion (8 elems/thread)
// ---------------------------------------------------------------------------
struct Half8 { __half2 h[4]; };

__global__ void __launch_bounds__(256)
f32_to_f16_kernel(const float* __restrict__ src, __half* __restrict__ dst, int n8)
{
    int i = blockIdx.x * blockDim.x + threadIdx.x;
    if (i >= n8) return;
    const float4* s4 = (const float4*)src;
    float4 a = s4[2 * i];
    float4 b = s4[2 * i + 1];
    Half8 o;
    o.h[0] = __floats2half2_rn(a.x, a.y);
    o.h[1] = __floats2half2_rn(a.z, a.w);
    o.h[2] = __floats2half2_rn(b.x, b.y);
    o.h[3] = __floats2half2_rn(b.z, b.w);
    ((Half8*)dst)[i] = o;
}

// ---------------------------------------------------------------------------
// P[0:numS]      = emb_s @ W1[0:64,:]  + b1   (fp16 output)
// P[numS:+numA]  = emb_a @ W1[64:128,:]
// 128 threads/block (thread j = column j), 16 rows/block, W half in regs.
// ---------------------------------------------------------------------------
__global__ void __launch_bounds__(128)
precompute_P_kernel(const float* __restrict__ emb_s,
                    const float* __restrict__ emb_a,
                    const float* __restrict__ W1,
                    const float* __restrict__ b1,
                    __half* __restrict__ P,
                    int numS, int numA)
{
    const int col = threadIdx.x;
    const int sBlocks = (numS + 15) / 16;
    const bool isS = ((int)blockIdx.x < sBlocks);

    const float* Wh = isS ? W1 : (W1 + D_NODE * H_DIM);
    float w[D_NODE];
#pragma unroll
    for (int k = 0; k < D_NODE; ++k) w[k] = Wh[k * H_DIM + col];

    const float bias = isS ? b1[col] : 0.0f;
    const int rowBase = (isS ? (int)blockIdx.x : ((int)blockIdx.x - sBlocks)) * 16;
    const float* etab = isS ? emb_s : emb_a;
    const int rowsTot = isS ? numS : numA;
    const int pOff = isS ? 0 : numS;

    for (int r = 0; r < 16; ++r) {
        const int row = rowBase + r;
        if (row >= rowsTot) break;
        const float* erow = etab + (size_t)row * D_NODE;
        float acc = bias;
#pragma unroll
        for (int k = 0; k < D_NODE; ++k)
            acc = fmaf(erow[k], w[k], acc);
        P[(size_t)(pOff + row) * H_DIM + col] = __float2half(acc);
    }
}

// ---------------------------------------------------------------------------
// Main edge pass: 8 lanes per edge.
//   cost = ||es-ea|| * sigmoid( dot(relu(P_s+P_a), W2) + b2 )
//   ex   = exp(-cost/temp)   (no seg-max needed: vals in [-20,0])
//   atomicAdd(segsum[s], ex)
// ---------------------------------------------------------------------------
__global__ void __launch_bounds__(256)
edge_main_kernel(const __half* __restrict__ e16s,
                 const __half* __restrict__ e16a,
                 const int* __restrict__ idx,
                 const __half* __restrict__ P,
                 const float* __restrict__ W2,
                 const float* __restrict__ b2,
                 const float* __restrict__ logT,
                 float* __restrict__ out_costs,
                 float* __restrict__ vals,        // stores ex
                 float* __restrict__ segsum,
                 int E, int numS)
{
    const int gid = blockIdx.x * 256 + (int)threadIdx.x;
    const int e = gid >> 3;
    const int t = gid & 7;
    if (e >= E) return;

    const int s = idx[e];
    const int a = idx[E + e];

    // --- norm partial: 8 halves of es/ea per lane ---
    const uint4* es8 = (const uint4*)(e16s + (size_t)s * D_NODE);
    const uint4* ea8 = (const uint4*)(e16a + (size_t)a * D_NODE);
    uint4 xs = es8[t];
    uint4 xa = ea8[t];
    const __half2* hs = (const __half2*)&xs;
    const __half2* ha = (const __half2*)&xa;
    float nacc = 0.0f;
#pragma unroll
    for (int k = 0; k < 4; ++k) {
        float2 fs = __half22float2(hs[k]);
        float2 fa = __half22float2(ha[k]);
        float d0 = fs.x - fa.x, d1 = fs.y - fa.y;
        nacc = fmaf(d0, d0, nacc);
        nacc = fmaf(d1, d1, nacc);
    }

    // --- gate partial: h-chunks t and t+8 (8 halves each) ---
    const uint4* ps8 = (const uint4*)(P + (size_t)s * H_DIM);
    const uint4* pa8 = (const uint4*)(P + (size_t)(numS + a) * H_DIM);
    const float4* w4 = (const float4*)W2;
    float g = 0.0f;
#pragma unroll
    for (int c = 0; c < 2; ++c) {
        const int chunk = t + c * 8;
        uint4 up = ps8[chunk];
        uint4 uq = pa8[chunk];
        const __half2* hp = (const __half2*)&up;
        const __half2* hq = (const __half2*)&uq;
        float4 w0 = w4[chunk * 2];
        float4 w1 = w4[chunk * 2 + 1];
        float wv[8] = {w0.x, w0.y, w0.z, w0.w, w1.x, w1.y, w1.z, w1.w};
#pragma unroll
        for (int k = 0; k < 4; ++k) {
            float2 fp = __half22float2(hp[k]);
            float2 fq = __half22float2(hq[k]);
            float h0 = fmaxf(fp.x + fq.x, 0.0f);
            float h1 = fmaxf(fp.y + fq.y, 0.0f);
            g = fmaf(h0, wv[2 * k], g);
            g = fmaf(h1, wv[2 * k + 1], g);
        }
    }

    // --- 8-lane reduction (groups are lane-aligned within the wave) ---
#pragma unroll
    for (int m = 1; m < 8; m <<= 1) {
        nacc += __shfl_xor(nacc, m);
        g    += __shfl_xor(g, m);
    }

    if (t == 0) {
        const float z = g + b2[0];
        const float gate = 1.0f / (1.0f + __expf(-z));
        const float cost = sqrtf(nacc) * gate;
        out_costs[e] = cost;
        const float temp = __expf(logT[0]);
        const float ex = __expf(-cost / temp);
        vals[e] = ex;
        atomicAdd(&segsum[s], ex);
    }
}

// ---------------------------------------------------------------------------
// edge_weights = ex / segsum[s]
// ---------------------------------------------------------------------------
__global__ void __launch_bounds__(256)
edge_norm_kernel(const int* __restrict__ idx,
                 const float* __restrict__ vals,
                 const float* __restrict__ segsum,
                 float* __restrict__ out_w,
                 int E)
{
    const int e = blockIdx.x * blockDim.x + threadIdx.x;
    if (e >= E) return;
    const int s = idx[e];
    out_w[e] = vals[e] / segsum[s];
}

// ---------------------------------------------------------------------------
extern "C" void kernel_launch(void* const* d_in, const int* in_sizes, int n_in,
                              void* d_out, int out_size, void* d_ws, size_t ws_size,
                              hipStream_t stream)
{
    const float* emb_s = (const float*)d_in[0];
    const float* emb_a = (const float*)d_in[1];
    const int*   idx   = (const int*)d_in[2];
    const float* W1    = (const float*)d_in[3];
    const float* b1    = (const float*)d_in[4];
    const float* W2    = (const float*)d_in[5];
    const float* b2    = (const float*)d_in[6];
    const float* logT  = (const float*)d_in[7];

    const int numS = in_sizes[0] / D_NODE;
    const int numA = in_sizes[1] / D_NODE;
    const int E    = in_sizes[2] / 2;

    float* out = (float*)d_out;            // [0,E) weights, [E,2E) costs

    // workspace layout (all fp16 counts are multiples of 8 -> 16B aligned)
    char* ws = (char*)d_ws;
    __half* P    = (__half*)ws;                        ws += (size_t)(numS + numA) * H_DIM * sizeof(__half);
    __half* e16s = (__half*)ws;                        ws += (size_t)numS * D_NODE * sizeof(__half);
    __half* e16a = (__half*)ws;                        ws += (size_t)numA * D_NODE * sizeof(__half);
    float*  vals = (float*)ws;                         ws += (size_t)E * sizeof(float);
    float*  segsum = (float*)ws;

    // independent prep work
    {
        const int n8s = numS * D_NODE / 8;
        const int n8a = numA * D_NODE / 8;
        f32_to_f16_kernel<<<(n8s + 255) / 256, 256, 0, stream>>>(emb_s, e16s, n8s);
        f32_to_f16_kernel<<<(n8a + 255) / 256, 256, 0, stream>>>(emb_a, e16a, n8a);
    }
    {
        const int pBlocks = (numS + 15) / 16 + (numA + 15) / 16;
        precompute_P_kernel<<<pBlocks, 128, 0, stream>>>(emb_s, emb_a, W1, b1, P,
                                                         numS, numA);
    }
    hipMemsetAsync(segsum, 0, (size_t)numS * sizeof(float), stream);

    // main edge pass (8 lanes/edge)
    {
        const long long threads = (long long)E * 8;
        const int blocks = (int)((threads + 255) / 256);
        edge_main_kernel<<<blocks, 256, 0, stream>>>(e16s, e16a, idx, P, W2, b2,
                                                     logT, out + E, vals, segsum,
                                                     E, numS);
    }

    edge_norm_kernel<<<(E + 255) / 256, 256, 0, stream>>>(idx, vals, segsum, out, E);
}